// Round 10
// baseline (310.254 us; speedup 1.0000x reference)
//
#include <hip/hip_runtime.h>

#define CDIV(a,b) (((a)+(b)-1)/(b))
#define NPB 256     // nodes per bucket; bucket(d) = d >> 8
#define PCHUNK 8192 // edges per partition block

typedef __attribute__((ext_vector_type(8))) short bf16x8;
typedef __attribute__((ext_vector_type(8))) unsigned short u16x8;
typedef __attribute__((ext_vector_type(4))) float f32x4;

__device__ __forceinline__ unsigned short f2bf(float x){
    unsigned int u = __float_as_uint(x);
    unsigned int r = u + 0x7FFFu + ((u >> 16) & 1u);   // RNE
    return (unsigned short)(r >> 16);
}
__device__ __forceinline__ float bf2f(unsigned short h){
    return __uint_as_float(((unsigned int)h) << 16);
}

// ---------------- wsplit for all 4 weight matrices in one launch ----------------
__global__ __launch_bounds__(256) void hg_wsplit_all(const float* __restrict__ W1u, const float* __restrict__ W1i,
                                                     const float* __restrict__ W2u, const float* __restrict__ W2i,
                                                     unsigned short* __restrict__ Bhi, unsigned short* __restrict__ Blo){
    const int sid = blockIdx.x*256 + threadIdx.x;   // 0..3071
    if (sid >= 3072) return;
    const float* W; int slot, base;
    if (sid < 1024)      { W = W1u; slot = sid;        base = 0;     }
    else if (sid < 2048) { W = W1i; slot = sid - 1024; base = 8192;  }
    else if (sid < 2560) { W = W2u; slot = sid - 2048; base = 16384; }
    else                 { W = W2i; slot = sid - 2560; base = 20480; }
    const int l  = slot & 63;
    const int ct = (slot >> 6) & 3;
    const int ks = slot >> 8;
    const int kb = ks*32 + (l >> 4)*8;
    const int c  = ct*16 + (l & 15);
    #pragma unroll
    for (int j = 0; j < 8; ++j){
        const float w = W[(size_t)(kb + j)*64 + c];
        const unsigned short h = f2bf(w);
        Bhi[(size_t)base + (size_t)slot*8 + j] = h;
        Blo[(size_t)base + (size_t)slot*8 + j] = f2bf(w - bf2f(h));
    }
}

// ---------------- dual bucket histogram ----------------
__global__ __launch_bounds__(256) void hg_bhist2(const int* __restrict__ dstU, const int* __restrict__ dstI,
                                                 int* __restrict__ bhU, int* __restrict__ bhI,
                                                 int EU, int EI, int nbU, int NB){
    extern __shared__ int sh[];
    const int type = (blockIdx.x >= nbU);
    const int blk  = type ? blockIdx.x - nbU : blockIdx.x;
    const int* dst = type ? dstI : dstU;
    int* bh        = type ? bhI  : bhU;
    const int E    = type ? EI   : EU;
    for (int i = threadIdx.x; i < NB; i += 256) sh[i] = 0;
    __syncthreads();
    const int e0 = blk * 4096;
    const int eend = min(e0 + 4096, E);
    for (int e = e0 + threadIdx.x; e < eend; e += 256)
        atomicAdd(&sh[dst[e] >> 8], 1);
    __syncthreads();
    for (int i = threadIdx.x; i < NB; i += 256)
        if (sh[i]) atomicAdd(&bh[i], sh[i]);
}

// ---------------- dual exclusive scan (block 0 = user, block 1 = item); also fills gcursor ----
__global__ __launch_bounds__(1024) void hg_bscan2(const int* __restrict__ bhU, const int* __restrict__ bhI,
                                                  int* __restrict__ boffU, int* __restrict__ boffI,
                                                  int* __restrict__ gcurU, int* __restrict__ gcurI,
                                                  int NB, int EU, int EI){
    __shared__ int sh[1024];
    const int type = blockIdx.x;
    const int* bh = type ? bhI : bhU;
    int* boff     = type ? boffI : boffU;
    int* gcur     = type ? gcurI : gcurU;
    const int E   = type ? EI : EU;
    const int t = threadIdx.x;
    const int v = (t < NB) ? bh[t] : 0;
    sh[t] = v;
    __syncthreads();
    for (int off = 1; off < 1024; off <<= 1){
        int x = 0;
        if (t >= off) x = sh[t-off];
        __syncthreads();
        if (t >= off) sh[t] += x;
        __syncthreads();
    }
    if (t < NB){ const int e = sh[t] - v; boff[t] = e; gcur[t] = e; }
    if (t == 0) boff[NB] = E;
}

// ---------------- dual partition, LDS-staged for coalesced global writes ----------------
// per block: histogram -> per-bucket global base (1 atomic/bucket) + in-block scan ->
// counting-sort into LDS stage[] (bucket-major) -> streamed coalesced write-out
__global__ __launch_bounds__(256) void hg_partition3(const int* __restrict__ eiU, const int* __restrict__ eiI,
                                                     int* __restrict__ gcurU, int* __restrict__ gcurI,
                                                     unsigned int* __restrict__ bkU, unsigned int* __restrict__ bkI,
                                                     int EU, int EI, int nbU, int NB){
    extern __shared__ int sh[];
    int* lhist = sh;                 // NB+1 (becomes lofs after scan; [NB] = sentinel)
    int* lcur  = lhist + NB + 1;     // NB
    int* lbase = lcur + NB;          // NB
    int* sc    = lbase + NB;         // 256
    unsigned int* stage = (unsigned int*)(sc + 256);   // PCHUNK

    const int type = (blockIdx.x >= nbU);
    const int blk  = type ? blockIdx.x - nbU : blockIdx.x;
    const int E    = type ? EI : EU;
    const int* src = type ? eiI : eiU;
    const int* dst = src + E;
    int* gcur      = type ? gcurI : gcurU;
    unsigned int* bucketed = type ? bkI : bkU;

    const int t  = threadIdx.x;
    const int e0 = blk * PCHUNK;
    const int eend = min(e0 + PCHUNK, E);
    const int cnt  = eend - e0;

    // phase 1: local histogram
    for (int i = t; i < NB; i += 256) lhist[i] = 0;
    __syncthreads();
    #pragma unroll
    for (int j = 0; j < PCHUNK/256; ++j){
        const int e = e0 + t + j*256;
        if (e < eend) atomicAdd(&lhist[dst[e] >> 8], 1);
    }
    __syncthreads();

    // phase 2: per-bucket global base + in-block exclusive scan (2 elems/thread)
    const int i0 = 2*t, i1 = 2*t + 1;
    const int c0 = (i0 < NB) ? lhist[i0] : 0;
    const int c1 = (i1 < NB) ? lhist[i1] : 0;
    if (i0 < NB) lbase[i0] = c0 ? atomicAdd(&gcur[i0], c0) : 0;
    if (i1 < NB) lbase[i1] = c1 ? atomicAdd(&gcur[i1], c1) : 0;
    const int s = c0 + c1;
    sc[t] = s;
    __syncthreads();
    for (int off = 1; off < 256; off <<= 1){
        int x = 0;
        if (t >= off) x = sc[t-off];
        __syncthreads();
        if (t >= off) sc[t] += x;
        __syncthreads();
    }
    const int excl = sc[t] - s;
    if (i0 < NB){ lhist[i0] = excl;      lcur[i0] = excl; }
    if (i1 < NB){ lhist[i1] = excl + c0; lcur[i1] = excl + c0; }
    if (t == 0) lhist[NB] = cnt;
    __syncthreads();

    // phase 3: counting-sort packed words into LDS stage (bucket-major)
    #pragma unroll
    for (int j = 0; j < PCHUNK/256; ++j){
        const int e = e0 + t + j*256;
        if (e < eend){
            const int d = dst[e];
            const int p = atomicAdd(&lcur[d >> 8], 1);
            stage[p] = (unsigned int)src[e] | ((unsigned int)(d & 255) << 24);
        }
    }
    __syncthreads();

    // phase 4: streamed write-out; consecutive t -> consecutive addresses within a run
    for (int i = t; i < cnt; i += 256){
        int lo = 0, hi = NB;                 // upper_bound over lofs[0..NB]
        while (lo < hi){
            const int mid = (lo + hi) >> 1;
            if (lhist[mid] <= i) lo = mid + 1; else hi = mid;
        }
        const int b = lo - 1;
        bucketed[lbase[b] + (i - lhist[b])] = stage[i];
    }
}

// ---------------- dual per-bucket deg/dinv/rowptr/counting-sort ----------------
__global__ __launch_bounds__(256) void hg_bucket_build2(const unsigned int* __restrict__ bkU, const unsigned int* __restrict__ bkI,
                                                        const int* __restrict__ boffU, const int* __restrict__ boffI,
                                                        float* __restrict__ dinvU, float* __restrict__ dinvI,
                                                        int* __restrict__ rowptrU, int* __restrict__ rowptrI,
                                                        int* __restrict__ csrU, int* __restrict__ csrI,
                                                        int NU, int NI, int EU, int EI, int nbU){
    __shared__ int hist[NPB];
    __shared__ int sc[NPB];
    __shared__ int cur[NPB];
    const int type = (blockIdx.x >= nbU);
    const int b    = type ? blockIdx.x - nbU : blockIdx.x;
    const unsigned int* bucketed = type ? bkI : bkU;
    const int* boff = type ? boffI : boffU;
    float* dinv     = type ? dinvI : dinvU;
    int* rowptr     = type ? rowptrI : rowptrU;
    int* csr_src    = type ? csrI : csrU;
    const int N     = type ? NI : NU;
    const int E     = type ? EI : EU;

    const int t   = threadIdx.x;
    const int beg = boff[b], end = boff[b+1];
    hist[t] = 0;
    __syncthreads();
    for (int i = beg + t; i < end; i += 256)
        atomicAdd(&hist[bucketed[i] >> 24], 1);
    __syncthreads();
    const int d = hist[t];
    sc[t] = d;
    __syncthreads();
    for (int off = 1; off < 256; off <<= 1){
        int x = 0;
        if (t >= off) x = sc[t-off];
        __syncthreads();
        if (t >= off) sc[t] += x;
        __syncthreads();
    }
    const int excl = sc[t] - d;
    const int v = b*NPB + t;
    if (v < N){
        dinv[v]   = rsqrtf((float)(d + 1));     // +1 self-loop
        rowptr[v] = beg + excl;
    }
    if (b == 0 && t == 0) rowptr[N] = E;
    cur[t] = beg + excl;
    __syncthreads();
    for (int i = beg + t; i < end; i += 256){
        const unsigned int w = bucketed[i];
        const int p = atomicAdd(&cur[w >> 24], 1);
        csr_src[p] = (int)(w & 0x00FFFFFFu);
    }
}

// ---------------- dual MFMA GEMM: Gbf[v][j] = bf16((X[v,:] @ W[:,j]) * dinv[v]) ----------------
template<int K>
__global__ __launch_bounds__(256) void hg_gemm_mfma2(const float* __restrict__ XU, const float* __restrict__ XI,
                                                     const unsigned short* __restrict__ Bhi, const unsigned short* __restrict__ Blo,
                                                     int baseU, int baseI,
                                                     const float* __restrict__ dinvU, const float* __restrict__ dinvI,
                                                     unsigned short* __restrict__ GU, unsigned short* __restrict__ GI,
                                                     int NU, int NI, int nbU){
    const int type = (blockIdx.x >= nbU);
    const int blk  = type ? blockIdx.x - nbU : blockIdx.x;
    const float* X = type ? XI : XU;
    const float* dinv = type ? dinvI : dinvU;
    unsigned short* G = type ? GI : GU;
    const int N    = type ? NI : NU;
    const unsigned short* Bh = Bhi + (type ? baseI : baseU);
    const unsigned short* Bl = Blo + (type ? baseI : baseU);

    const int l = threadIdx.x & 63;
    const int w = threadIdx.x >> 6;
    const int row0 = blk*64 + w*16;
    if (row0 >= N) return;

    f32x4 acc[4];
    #pragma unroll
    for (int ct = 0; ct < 4; ++ct) acc[ct] = (f32x4){0.f,0.f,0.f,0.f};

    const int rA = row0 + (l & 15);
    const int kg = (l >> 4) * 8;
    const bool rowok = (rA < N);
    const float* xrow = X + (size_t)rA * K;

    #pragma unroll
    for (int ks = 0; ks < K/32; ++ks){
        float xv[8];
        if (rowok){
            const float4 a = *(const float4*)(xrow + ks*32 + kg);
            const float4 b = *(const float4*)(xrow + ks*32 + kg + 4);
            xv[0]=a.x; xv[1]=a.y; xv[2]=a.z; xv[3]=a.w;
            xv[4]=b.x; xv[5]=b.y; xv[6]=b.z; xv[7]=b.w;
        } else {
            #pragma unroll
            for (int j = 0; j < 8; ++j) xv[j] = 0.f;
        }
        bf16x8 ahi, alo;
        #pragma unroll
        for (int j = 0; j < 8; ++j){
            const unsigned short h = f2bf(xv[j]);
            ahi[j] = (short)h;
            alo[j] = (short)f2bf(xv[j] - bf2f(h));
        }
        #pragma unroll
        for (int ct = 0; ct < 4; ++ct){
            const bf16x8 bhi = *(const bf16x8*)(Bh + ((size_t)(ks*4 + ct)*64 + l)*8);
            const bf16x8 blo = *(const bf16x8*)(Bl + ((size_t)(ks*4 + ct)*64 + l)*8);
            acc[ct] = __builtin_amdgcn_mfma_f32_16x16x32_bf16(ahi, bhi, acc[ct], 0, 0, 0);
            acc[ct] = __builtin_amdgcn_mfma_f32_16x16x32_bf16(alo, bhi, acc[ct], 0, 0, 0);
            acc[ct] = __builtin_amdgcn_mfma_f32_16x16x32_bf16(ahi, blo, acc[ct], 0, 0, 0);
        }
    }

    const int orow0 = row0 + (l >> 4)*4;
    const int ocol  = l & 15;
    #pragma unroll
    for (int r = 0; r < 4; ++r){
        const int orow = orow0 + r;
        if (orow < N){
            const float dv = dinv[orow];
            #pragma unroll
            for (int ct = 0; ct < 4; ++ct)
                G[(size_t)orow*64 + ct*16 + ocol] = f2bf(acc[ct][r] * dv);
        }
    }
}

// ---------------- dual gather-aggregate (bf16 G): 8 nodes/wave, 8 lanes x bf16x8 per node ----
__global__ __launch_bounds__(256) void hg_aggregate2(const unsigned short* __restrict__ gU, const unsigned short* __restrict__ gI,
                                                     const int* __restrict__ csrU, const int* __restrict__ csrI,
                                                     const int* __restrict__ rowptrU, const int* __restrict__ rowptrI,
                                                     const float* __restrict__ dinvU, const float* __restrict__ dinvI,
                                                     const float* __restrict__ bU, const float* __restrict__ bI,
                                                     float* __restrict__ outU, float* __restrict__ outI,
                                                     int NU, int NI, int nbU){
    const int type = (blockIdx.x >= nbU);
    const int blk  = type ? blockIdx.x - nbU : blockIdx.x;
    const unsigned short* g = type ? gI : gU;
    const int* csr_src = type ? csrI : csrU;
    const int* rowptr  = type ? rowptrI : rowptrU;
    const float* dinv  = type ? dinvI : dinvU;
    const float* b     = type ? bI : bU;
    float* outp        = type ? outI : outU;
    const int N        = type ? NI : NU;

    const int wave = (blk*256 + (int)threadIdx.x) >> 6;
    const int sub  = (threadIdx.x >> 3) & 7;
    const int c8   = (threadIdx.x & 7) << 3;
    const int v    = wave*8 + sub;
    const bool ok  = (v < N);

    int beg = 0, cnt = 0;
    if (ok){ beg = rowptr[v]; cnt = rowptr[v+1] - beg; }

    float acc[8];
    #pragma unroll
    for (int j = 0; j < 8; ++j) acc[j] = 0.f;
    if (ok){
        const u16x8 s = *(const u16x8*)(g + (size_t)v*64 + c8);
        #pragma unroll
        for (int j = 0; j < 8; ++j) acc[j] = bf2f(s[j]);
    }

    int i = 0;
    for (; i + 8 <= cnt; i += 8){
        const int s0 = csr_src[beg+i+0]; const int s1 = csr_src[beg+i+1];
        const int s2 = csr_src[beg+i+2]; const int s3 = csr_src[beg+i+3];
        const int s4 = csr_src[beg+i+4]; const int s5 = csr_src[beg+i+5];
        const int s6 = csr_src[beg+i+6]; const int s7 = csr_src[beg+i+7];
        const u16x8 x0 = *(const u16x8*)(g + (size_t)s0*64 + c8);
        const u16x8 x1 = *(const u16x8*)(g + (size_t)s1*64 + c8);
        const u16x8 x2 = *(const u16x8*)(g + (size_t)s2*64 + c8);
        const u16x8 x3 = *(const u16x8*)(g + (size_t)s3*64 + c8);
        const u16x8 x4 = *(const u16x8*)(g + (size_t)s4*64 + c8);
        const u16x8 x5 = *(const u16x8*)(g + (size_t)s5*64 + c8);
        const u16x8 x6 = *(const u16x8*)(g + (size_t)s6*64 + c8);
        const u16x8 x7 = *(const u16x8*)(g + (size_t)s7*64 + c8);
        #pragma unroll
        for (int j = 0; j < 8; ++j){
            acc[j] += (bf2f(x0[j]) + bf2f(x1[j])) + (bf2f(x2[j]) + bf2f(x3[j]))
                    + (bf2f(x4[j]) + bf2f(x5[j])) + (bf2f(x6[j]) + bf2f(x7[j]));
        }
    }
    for (; i + 4 <= cnt; i += 4){
        const int s0 = csr_src[beg+i+0]; const int s1 = csr_src[beg+i+1];
        const int s2 = csr_src[beg+i+2]; const int s3 = csr_src[beg+i+3];
        const u16x8 x0 = *(const u16x8*)(g + (size_t)s0*64 + c8);
        const u16x8 x1 = *(const u16x8*)(g + (size_t)s1*64 + c8);
        const u16x8 x2 = *(const u16x8*)(g + (size_t)s2*64 + c8);
        const u16x8 x3 = *(const u16x8*)(g + (size_t)s3*64 + c8);
        #pragma unroll
        for (int j = 0; j < 8; ++j)
            acc[j] += (bf2f(x0[j]) + bf2f(x1[j])) + (bf2f(x2[j]) + bf2f(x3[j]));
    }
    for (; i < cnt; ++i){
        const u16x8 x0 = *(const u16x8*)(g + (size_t)csr_src[beg+i]*64 + c8);
        #pragma unroll
        for (int j = 0; j < 8; ++j) acc[j] += bf2f(x0[j]);
    }

    if (ok){
        const float dv = dinv[v];
        float4 r0, r1;
        const float4 b0 = *(const float4*)(b + c8);
        const float4 b1 = *(const float4*)(b + c8 + 4);
        r0.x = fmaxf(fmaf(acc[0], dv, b0.x), 0.f);
        r0.y = fmaxf(fmaf(acc[1], dv, b0.y), 0.f);
        r0.z = fmaxf(fmaf(acc[2], dv, b0.z), 0.f);
        r0.w = fmaxf(fmaf(acc[3], dv, b0.w), 0.f);
        r1.x = fmaxf(fmaf(acc[4], dv, b1.x), 0.f);
        r1.y = fmaxf(fmaf(acc[5], dv, b1.y), 0.f);
        r1.z = fmaxf(fmaf(acc[6], dv, b1.z), 0.f);
        r1.w = fmaxf(fmaf(acc[7], dv, b1.w), 0.f);
        *(float4*)(outp + (size_t)v*64 + c8)     = r0;
        *(float4*)(outp + (size_t)v*64 + c8 + 4) = r1;
    }
}

// ---------------- dual head ----------------
__global__ __launch_bounds__(256) void hg_head2(const float* __restrict__ HU, const float* __restrict__ HI,
                                                const float* __restrict__ WlU, const float* __restrict__ WlI,
                                                const float* __restrict__ blU, const float* __restrict__ blI,
                                                float* __restrict__ outU, float* __restrict__ outI,
                                                int NU, int NI, int nbU){
    const int type = (blockIdx.x >= nbU);
    const int blk  = type ? blockIdx.x - nbU : blockIdx.x;
    const float* H  = type ? HI : HU;
    const float* Wl = type ? WlI : WlU;
    const float* bl = type ? blI : blU;
    float* outp     = type ? outI : outU;
    const int N     = type ? NI : NU;

    int v = blk*256 + threadIdx.x;
    if (v >= N) return;
    const float* h = H + (size_t)v*64;
    float a0 = bl[0], a1 = bl[1];
    #pragma unroll
    for (int k4 = 0; k4 < 16; ++k4) {
        const float4 x = *(const float4*)(h + k4*4);
        const float4 wA = *(const float4*)(Wl + k4*8 + 0);
        const float4 wB = *(const float4*)(Wl + k4*8 + 4);
        a0 = fmaf(x.x, wA.x, a0); a1 = fmaf(x.x, wA.y, a1);
        a0 = fmaf(x.y, wA.z, a0); a1 = fmaf(x.y, wA.w, a1);
        a0 = fmaf(x.z, wB.x, a0); a1 = fmaf(x.z, wB.y, a1);
        a0 = fmaf(x.w, wB.z, a0); a1 = fmaf(x.w, wB.w, a1);
    }
    float2 r; r.x = a0; r.y = a1;
    *(float2*)(outp + (size_t)v*2) = r;
}

extern "C" void kernel_launch(void* const* d_in, const int* in_sizes, int n_in,
                              void* d_out, int out_size, void* d_ws, size_t ws_size,
                              hipStream_t stream) {
    const float* x_user = (const float*)d_in[0];
    const float* x_item = (const float*)d_in[1];
    const int*  ei_user = (const int*)d_in[2];
    const int*  ei_item = (const int*)d_in[3];
    const float* W1_user = (const float*)d_in[4];
    const float* b1_user = (const float*)d_in[5];
    const float* W1_item = (const float*)d_in[6];
    const float* b1_item = (const float*)d_in[7];
    const float* W2_user = (const float*)d_in[8];
    const float* b2_user = (const float*)d_in[9];
    const float* W2_item = (const float*)d_in[10];
    const float* b2_item = (const float*)d_in[11];
    const float* Wl_user = (const float*)d_in[12];
    const float* bl_user = (const float*)d_in[13];
    const float* Wl_item = (const float*)d_in[14];
    const float* bl_item = (const float*)d_in[15];

    const int NU = in_sizes[0] / 128;
    const int NI = in_sizes[1] / 128;
    const int EU = in_sizes[2] / 2;
    const int EI = in_sizes[3] / 2;
    const int NBU = CDIV(NU, NPB);
    const int NBI = CDIV(NI, NPB);

    char* w = (char*)d_ws;
    float* hFU = (float*)w;                     w += (size_t)NU * 64 * sizeof(float);
    float* hFI = (float*)w;                     w += (size_t)NI * 64 * sizeof(float);
    unsigned short* GU = (unsigned short*)w;    w += (size_t)NU * 64 * sizeof(unsigned short);
    unsigned short* GI = (unsigned short*)w;    w += (size_t)NI * 64 * sizeof(unsigned short);
    float* dinvU = (float*)w;                   w += (size_t)NU * sizeof(float);
    float* dinvI = (float*)w;                   w += (size_t)NI * sizeof(float);
    int* rowptrU = (int*)w;                     w += ((size_t)NU + 1) * sizeof(int);
    int* rowptrI = (int*)w;                     w += ((size_t)NI + 1) * sizeof(int);
    int* csrU = (int*)w;                        w += (size_t)EU * sizeof(int);
    int* csrI = (int*)w;                        w += (size_t)EI * sizeof(int);
    unsigned int* bkU = (unsigned int*)w;       w += (size_t)EU * sizeof(int);
    unsigned int* bkI = (unsigned int*)w;       w += (size_t)EI * sizeof(int);
    int* bhU = (int*)w;                         w += (size_t)NBU * sizeof(int);
    int* bhI = (int*)w;                         w += (size_t)NBI * sizeof(int);   // contiguous with bhU
    int* boffU = (int*)w;                       w += ((size_t)NBU + 1) * sizeof(int);
    int* boffI = (int*)w;                       w += ((size_t)NBI + 1) * sizeof(int);
    int* gcurU = (int*)w;                       w += (size_t)NBU * sizeof(int);
    int* gcurI = (int*)w;                       w += (size_t)NBI * sizeof(int);
    unsigned short* Bhi = (unsigned short*)w;   w += (size_t)24576 * sizeof(unsigned short);
    unsigned short* Blo = (unsigned short*)w;   w += (size_t)24576 * sizeof(unsigned short);

    float* out  = (float*)d_out;
    float* outU = out;
    float* outI = out + (size_t)2 * NU;

    const int NB = (NBU > NBI) ? NBU : NBI;

    // weight prep (independent of everything else)
    hg_wsplit_all<<<12, 256, 0, stream>>>(W1_user, W1_item, W2_user, W2_item, Bhi, Blo);

    // CSR build, both types in each launch
    hipMemsetAsync(bhU, 0, ((size_t)NBU + NBI) * sizeof(int), stream);
    const int hbUc = CDIV(EU, 4096), hbIc = CDIV(EI, 4096);
    hg_bhist2<<<hbUc + hbIc, 256, NB*sizeof(int), stream>>>(ei_user + EU, ei_item + EI, bhU, bhI, EU, EI, hbUc, NB);
    hg_bscan2<<<2, 1024, 0, stream>>>(bhU, bhI, boffU, boffI, gcurU, gcurI, NB, EU, EI);
    const int pbU = CDIV(EU, PCHUNK), pbI = CDIV(EI, PCHUNK);
    const size_t p3lds = (size_t)(3*NB + 1 + 256 + PCHUNK) * sizeof(int);
    hg_partition3<<<pbU + pbI, 256, p3lds, stream>>>(ei_user, ei_item, gcurU, gcurI, bkU, bkI, EU, EI, pbU, NB);
    hg_bucket_build2<<<NBU + NBI, 256, 0, stream>>>(bkU, bkI, boffU, boffI, dinvU, dinvI,
                                                    rowptrU, rowptrI, csrU, csrI, NU, NI, EU, EI, NBU);

    // layer 1 (K=128): x -> G -> hF
    const int gbU = CDIV(NU, 64), gbI = CDIV(NI, 64);
    hg_gemm_mfma2<128><<<gbU + gbI, 256, 0, stream>>>(x_user, x_item, Bhi, Blo, 0, 8192,
                                                      dinvU, dinvI, GU, GI, NU, NI, gbU);
    const int abU = CDIV(NU, 32), abI = CDIV(NI, 32);
    hg_aggregate2<<<abU + abI, 256, 0, stream>>>(GU, GI, csrU, csrI, rowptrU, rowptrI,
                                                 dinvU, dinvI, b1_user, b1_item, hFU, hFI, NU, NI, abU);

    // layer 2 (K=64): hF -> G -> hF
    hg_gemm_mfma2<64><<<gbU + gbI, 256, 0, stream>>>(hFU, hFI, Bhi, Blo, 16384, 20480,
                                                     dinvU, dinvI, GU, GI, NU, NI, gbU);
    hg_aggregate2<<<abU + abI, 256, 0, stream>>>(GU, GI, csrU, csrI, rowptrU, rowptrI,
                                                 dinvU, dinvI, b2_user, b2_item, hFU, hFI, NU, NI, abU);

    // head
    const int hdU = CDIV(NU, 256), hdI = CDIV(NI, 256);
    hg_head2<<<hdU + hdI, 256, 0, stream>>>(hFU, hFI, Wl_user, Wl_item, bl_user, bl_item,
                                            outU, outI, NU, NI, hdU);
}

// Round 11
// 306.569 us; speedup vs baseline: 1.0120x; 1.0120x over previous
//
#include <hip/hip_runtime.h>

#define CDIV(a,b) (((a)+(b)-1)/(b))
#define NPB 256     // nodes per bucket; bucket(d) = d >> 8
#define PCHUNK 2048 // edges per partition block

typedef __attribute__((ext_vector_type(8))) short bf16x8;
typedef __attribute__((ext_vector_type(8))) unsigned short u16x8;
typedef __attribute__((ext_vector_type(4))) float f32x4;

__device__ __forceinline__ unsigned short f2bf(float x){
    unsigned int u = __float_as_uint(x);
    unsigned int r = u + 0x7FFFu + ((u >> 16) & 1u);   // RNE
    return (unsigned short)(r >> 16);
}
__device__ __forceinline__ float bf2f(unsigned short h){
    return __uint_as_float(((unsigned int)h) << 16);
}

// ---------------- wsplit for all 4 weight matrices in one launch ----------------
__global__ __launch_bounds__(256) void hg_wsplit_all(const float* __restrict__ W1u, const float* __restrict__ W1i,
                                                     const float* __restrict__ W2u, const float* __restrict__ W2i,
                                                     unsigned short* __restrict__ Bhi, unsigned short* __restrict__ Blo){
    const int sid = blockIdx.x*256 + threadIdx.x;   // 0..3071
    if (sid >= 3072) return;
    const float* W; int slot, base;
    if (sid < 1024)      { W = W1u; slot = sid;        base = 0;     }
    else if (sid < 2048) { W = W1i; slot = sid - 1024; base = 8192;  }
    else if (sid < 2560) { W = W2u; slot = sid - 2048; base = 16384; }
    else                 { W = W2i; slot = sid - 2560; base = 20480; }
    const int l  = slot & 63;
    const int ct = (slot >> 6) & 3;
    const int ks = slot >> 8;
    const int kb = ks*32 + (l >> 4)*8;
    const int c  = ct*16 + (l & 15);
    #pragma unroll
    for (int j = 0; j < 8; ++j){
        const float w = W[(size_t)(kb + j)*64 + c];
        const unsigned short h = f2bf(w);
        Bhi[(size_t)base + (size_t)slot*8 + j] = h;
        Blo[(size_t)base + (size_t)slot*8 + j] = f2bf(w - bf2f(h));
    }
}

// ---------------- dual bucket histogram ----------------
__global__ __launch_bounds__(256) void hg_bhist2(const int* __restrict__ dstU, const int* __restrict__ dstI,
                                                 int* __restrict__ bhU, int* __restrict__ bhI,
                                                 int EU, int EI, int nbU, int NB){
    extern __shared__ int sh[];
    const int type = (blockIdx.x >= nbU);
    const int blk  = type ? blockIdx.x - nbU : blockIdx.x;
    const int* dst = type ? dstI : dstU;
    int* bh        = type ? bhI  : bhU;
    const int E    = type ? EI   : EU;
    for (int i = threadIdx.x; i < NB; i += 256) sh[i] = 0;
    __syncthreads();
    const int e0 = blk * 4096;
    const int eend = min(e0 + 4096, E);
    for (int e = e0 + threadIdx.x; e < eend; e += 256)
        atomicAdd(&sh[dst[e] >> 8], 1);
    __syncthreads();
    for (int i = threadIdx.x; i < NB; i += 256)
        if (sh[i]) atomicAdd(&bh[i], sh[i]);
}

// ---------------- dual exclusive scan (block 0 = user, block 1 = item); also fills gcursor ----
__global__ __launch_bounds__(1024) void hg_bscan2(const int* __restrict__ bhU, const int* __restrict__ bhI,
                                                  int* __restrict__ boffU, int* __restrict__ boffI,
                                                  int* __restrict__ gcurU, int* __restrict__ gcurI,
                                                  int NB, int EU, int EI){
    __shared__ int sh[1024];
    const int type = blockIdx.x;
    const int* bh = type ? bhI : bhU;
    int* boff     = type ? boffI : boffU;
    int* gcur     = type ? gcurI : gcurU;
    const int E   = type ? EI : EU;
    const int t = threadIdx.x;
    const int v = (t < NB) ? bh[t] : 0;
    sh[t] = v;
    __syncthreads();
    for (int off = 1; off < 1024; off <<= 1){
        int x = 0;
        if (t >= off) x = sh[t-off];
        __syncthreads();
        if (t >= off) sh[t] += x;
        __syncthreads();
    }
    if (t < NB){ const int e = sh[t] - v; boff[t] = e; gcur[t] = e; }
    if (t == 0) boff[NB] = E;
}

// ---------------- dual partition, LDS-staged, precomputed global addresses ----------------
// phases: reg-load edges + LDS hist -> per-bucket global base + in-block scan ->
// counting-sort into LDS stage[] while computing gaddr[] -> streamed coalesced copy-out
__global__ __launch_bounds__(256) void hg_partition4(const int* __restrict__ eiU, const int* __restrict__ eiI,
                                                     int* __restrict__ gcurU, int* __restrict__ gcurI,
                                                     unsigned int* __restrict__ bkU, unsigned int* __restrict__ bkI,
                                                     int EU, int EI, int nbU, int NB){
    extern __shared__ int sh[];
    int* lofs  = sh;                 // NB (exclusive offsets of this block's chunk)
    int* lcur  = lofs + NB;          // NB
    int* lbase = lcur + NB;          // NB
    int* sc    = lbase + NB;         // 256
    unsigned int* stage = (unsigned int*)(sc + 256);   // PCHUNK
    int* gaddr = (int*)(stage + PCHUNK);               // PCHUNK

    const int type = (blockIdx.x >= nbU);
    const int blk  = type ? blockIdx.x - nbU : blockIdx.x;
    const int E    = type ? EI : EU;
    const int* src = type ? eiI : eiU;
    const int* dst = src + E;
    int* gcur      = type ? gcurI : gcurU;
    unsigned int* bucketed = type ? bkI : bkU;

    const int t  = threadIdx.x;
    const int e0 = blk * PCHUNK;
    const int eend = min(e0 + PCHUNK, E);
    const int cnt  = eend - e0;

    // phase 1: load 8 edges/thread into registers (2x int4, contiguous 32B/lane) + LDS hist
    int se[8], de[8];
    for (int i = t; i < NB; i += 256) lofs[i] = 0;
    __syncthreads();
    const int eb = e0 + t*8;
    if (eb + 8 <= E){
        const int4 sa = *(const int4*)(src + eb);
        const int4 sb = *(const int4*)(src + eb + 4);
        const int4 da = *(const int4*)(dst + eb);
        const int4 db = *(const int4*)(dst + eb + 4);
        se[0]=sa.x; se[1]=sa.y; se[2]=sa.z; se[3]=sa.w;
        se[4]=sb.x; se[5]=sb.y; se[6]=sb.z; se[7]=sb.w;
        de[0]=da.x; de[1]=da.y; de[2]=da.z; de[3]=da.w;
        de[4]=db.x; de[5]=db.y; de[6]=db.z; de[7]=db.w;
    } else {
        #pragma unroll
        for (int j = 0; j < 8; ++j){
            const int e = eb + j;
            se[j] = (e < E) ? src[e] : -1;
            de[j] = (e < E) ? dst[e] : -1;
        }
    }
    #pragma unroll
    for (int j = 0; j < 8; ++j)
        if (de[j] >= 0) atomicAdd(&lofs[de[j] >> 8], 1);
    __syncthreads();

    // phase 2: per-bucket global base + in-block exclusive scan (2 elems/thread)
    const int i0 = 2*t, i1 = 2*t + 1;
    const int c0 = (i0 < NB) ? lofs[i0] : 0;
    const int c1 = (i1 < NB) ? lofs[i1] : 0;
    if (i0 < NB) lbase[i0] = c0 ? atomicAdd(&gcur[i0], c0) : 0;
    if (i1 < NB) lbase[i1] = c1 ? atomicAdd(&gcur[i1], c1) : 0;
    const int s = c0 + c1;
    sc[t] = s;
    __syncthreads();
    for (int off = 1; off < 256; off <<= 1){
        int x = 0;
        if (t >= off) x = sc[t-off];
        __syncthreads();
        if (t >= off) sc[t] += x;
        __syncthreads();
    }
    const int excl = sc[t] - s;
    __syncthreads();   // everyone read lofs counts before overwrite
    if (i0 < NB){ lofs[i0] = excl;      lcur[i0] = excl; }
    if (i1 < NB){ lofs[i1] = excl + c0; lcur[i1] = excl + c0; }
    __syncthreads();

    // phase 3: counting-sort into LDS stage; compute final global address per slot
    #pragma unroll
    for (int j = 0; j < 8; ++j){
        if (de[j] >= 0){
            const int b = de[j] >> 8;
            const int p = atomicAdd(&lcur[b], 1);
            stage[p] = (unsigned int)se[j] | ((unsigned int)(de[j] & 255) << 24);
            gaddr[p] = lbase[b] + (p - lofs[b]);
        }
    }
    __syncthreads();

    // phase 4: streamed copy-out (gaddr monotone within bucket runs -> coalesced)
    for (int i = t; i < cnt; i += 256)
        bucketed[gaddr[i]] = stage[i];
}

// ---------------- dual per-bucket deg/dinv/rowptr/counting-sort ----------------
__global__ __launch_bounds__(256) void hg_bucket_build2(const unsigned int* __restrict__ bkU, const unsigned int* __restrict__ bkI,
                                                        const int* __restrict__ boffU, const int* __restrict__ boffI,
                                                        float* __restrict__ dinvU, float* __restrict__ dinvI,
                                                        int* __restrict__ rowptrU, int* __restrict__ rowptrI,
                                                        int* __restrict__ csrU, int* __restrict__ csrI,
                                                        int NU, int NI, int EU, int EI, int nbU){
    __shared__ int hist[NPB];
    __shared__ int sc[NPB];
    __shared__ int cur[NPB];
    const int type = (blockIdx.x >= nbU);
    const int b    = type ? blockIdx.x - nbU : blockIdx.x;
    const unsigned int* bucketed = type ? bkI : bkU;
    const int* boff = type ? boffI : boffU;
    float* dinv     = type ? dinvI : dinvU;
    int* rowptr     = type ? rowptrI : rowptrU;
    int* csr_src    = type ? csrI : csrU;
    const int N     = type ? NI : NU;
    const int E     = type ? EI : EU;

    const int t   = threadIdx.x;
    const int beg = boff[b], end = boff[b+1];
    hist[t] = 0;
    __syncthreads();
    for (int i = beg + t; i < end; i += 256)
        atomicAdd(&hist[bucketed[i] >> 24], 1);
    __syncthreads();
    const int d = hist[t];
    sc[t] = d;
    __syncthreads();
    for (int off = 1; off < 256; off <<= 1){
        int x = 0;
        if (t >= off) x = sc[t-off];
        __syncthreads();
        if (t >= off) sc[t] += x;
        __syncthreads();
    }
    const int excl = sc[t] - d;
    const int v = b*NPB + t;
    if (v < N){
        dinv[v]   = rsqrtf((float)(d + 1));     // +1 self-loop
        rowptr[v] = beg + excl;
    }
    if (b == 0 && t == 0) rowptr[N] = E;
    cur[t] = beg + excl;
    __syncthreads();
    for (int i = beg + t; i < end; i += 256){
        const unsigned int w = bucketed[i];
        const int p = atomicAdd(&cur[w >> 24], 1);
        csr_src[p] = (int)(w & 0x00FFFFFFu);
    }
}

// ---------------- dual MFMA GEMM: Gbf[v][j] = bf16((X[v,:] @ W[:,j]) * dinv[v]) ----------------
template<int K>
__global__ __launch_bounds__(256) void hg_gemm_mfma2(const float* __restrict__ XU, const float* __restrict__ XI,
                                                     const unsigned short* __restrict__ Bhi, const unsigned short* __restrict__ Blo,
                                                     int baseU, int baseI,
                                                     const float* __restrict__ dinvU, const float* __restrict__ dinvI,
                                                     unsigned short* __restrict__ GU, unsigned short* __restrict__ GI,
                                                     int NU, int NI, int nbU){
    const int type = (blockIdx.x >= nbU);
    const int blk  = type ? blockIdx.x - nbU : blockIdx.x;
    const float* X = type ? XI : XU;
    const float* dinv = type ? dinvI : dinvU;
    unsigned short* G = type ? GI : GU;
    const int N    = type ? NI : NU;
    const unsigned short* Bh = Bhi + (type ? baseI : baseU);
    const unsigned short* Bl = Blo + (type ? baseI : baseU);

    const int l = threadIdx.x & 63;
    const int w = threadIdx.x >> 6;
    const int row0 = blk*64 + w*16;
    if (row0 >= N) return;

    f32x4 acc[4];
    #pragma unroll
    for (int ct = 0; ct < 4; ++ct) acc[ct] = (f32x4){0.f,0.f,0.f,0.f};

    const int rA = row0 + (l & 15);
    const int kg = (l >> 4) * 8;
    const bool rowok = (rA < N);
    const float* xrow = X + (size_t)rA * K;

    #pragma unroll
    for (int ks = 0; ks < K/32; ++ks){
        float xv[8];
        if (rowok){
            const float4 a = *(const float4*)(xrow + ks*32 + kg);
            const float4 b = *(const float4*)(xrow + ks*32 + kg + 4);
            xv[0]=a.x; xv[1]=a.y; xv[2]=a.z; xv[3]=a.w;
            xv[4]=b.x; xv[5]=b.y; xv[6]=b.z; xv[7]=b.w;
        } else {
            #pragma unroll
            for (int j = 0; j < 8; ++j) xv[j] = 0.f;
        }
        bf16x8 ahi, alo;
        #pragma unroll
        for (int j = 0; j < 8; ++j){
            const unsigned short h = f2bf(xv[j]);
            ahi[j] = (short)h;
            alo[j] = (short)f2bf(xv[j] - bf2f(h));
        }
        #pragma unroll
        for (int ct = 0; ct < 4; ++ct){
            const bf16x8 bhi = *(const bf16x8*)(Bh + ((size_t)(ks*4 + ct)*64 + l)*8);
            const bf16x8 blo = *(const bf16x8*)(Bl + ((size_t)(ks*4 + ct)*64 + l)*8);
            acc[ct] = __builtin_amdgcn_mfma_f32_16x16x32_bf16(ahi, bhi, acc[ct], 0, 0, 0);
            acc[ct] = __builtin_amdgcn_mfma_f32_16x16x32_bf16(alo, bhi, acc[ct], 0, 0, 0);
            acc[ct] = __builtin_amdgcn_mfma_f32_16x16x32_bf16(ahi, blo, acc[ct], 0, 0, 0);
        }
    }

    const int orow0 = row0 + (l >> 4)*4;
    const int ocol  = l & 15;
    #pragma unroll
    for (int r = 0; r < 4; ++r){
        const int orow = orow0 + r;
        if (orow < N){
            const float dv = dinv[orow];
            #pragma unroll
            for (int ct = 0; ct < 4; ++ct)
                G[(size_t)orow*64 + ct*16 + ocol] = f2bf(acc[ct][r] * dv);
        }
    }
}

// ---------------- dual gather-aggregate (bf16 G): 8 nodes/wave, 8 lanes x bf16x8 per node ----
__global__ __launch_bounds__(256) void hg_aggregate2(const unsigned short* __restrict__ gU, const unsigned short* __restrict__ gI,
                                                     const int* __restrict__ csrU, const int* __restrict__ csrI,
                                                     const int* __restrict__ rowptrU, const int* __restrict__ rowptrI,
                                                     const float* __restrict__ dinvU, const float* __restrict__ dinvI,
                                                     const float* __restrict__ bU, const float* __restrict__ bI,
                                                     float* __restrict__ outU, float* __restrict__ outI,
                                                     int NU, int NI, int nbU){
    const int type = (blockIdx.x >= nbU);
    const int blk  = type ? blockIdx.x - nbU : blockIdx.x;
    const unsigned short* g = type ? gI : gU;
    const int* csr_src = type ? csrI : csrU;
    const int* rowptr  = type ? rowptrI : rowptrU;
    const float* dinv  = type ? dinvI : dinvU;
    const float* b     = type ? bI : bU;
    float* outp        = type ? outI : outU;
    const int N        = type ? NI : NU;

    const int wave = (blk*256 + (int)threadIdx.x) >> 6;
    const int sub  = (threadIdx.x >> 3) & 7;
    const int c8   = (threadIdx.x & 7) << 3;
    const int v    = wave*8 + sub;
    const bool ok  = (v < N);

    int beg = 0, cnt = 0;
    if (ok){ beg = rowptr[v]; cnt = rowptr[v+1] - beg; }

    float acc[8];
    #pragma unroll
    for (int j = 0; j < 8; ++j) acc[j] = 0.f;
    if (ok){
        const u16x8 s = *(const u16x8*)(g + (size_t)v*64 + c8);
        #pragma unroll
        for (int j = 0; j < 8; ++j) acc[j] = bf2f(s[j]);
    }

    int i = 0;
    for (; i + 8 <= cnt; i += 8){
        const int s0 = csr_src[beg+i+0]; const int s1 = csr_src[beg+i+1];
        const int s2 = csr_src[beg+i+2]; const int s3 = csr_src[beg+i+3];
        const int s4 = csr_src[beg+i+4]; const int s5 = csr_src[beg+i+5];
        const int s6 = csr_src[beg+i+6]; const int s7 = csr_src[beg+i+7];
        const u16x8 x0 = *(const u16x8*)(g + (size_t)s0*64 + c8);
        const u16x8 x1 = *(const u16x8*)(g + (size_t)s1*64 + c8);
        const u16x8 x2 = *(const u16x8*)(g + (size_t)s2*64 + c8);
        const u16x8 x3 = *(const u16x8*)(g + (size_t)s3*64 + c8);
        const u16x8 x4 = *(const u16x8*)(g + (size_t)s4*64 + c8);
        const u16x8 x5 = *(const u16x8*)(g + (size_t)s5*64 + c8);
        const u16x8 x6 = *(const u16x8*)(g + (size_t)s6*64 + c8);
        const u16x8 x7 = *(const u16x8*)(g + (size_t)s7*64 + c8);
        #pragma unroll
        for (int j = 0; j < 8; ++j){
            acc[j] += (bf2f(x0[j]) + bf2f(x1[j])) + (bf2f(x2[j]) + bf2f(x3[j]))
                    + (bf2f(x4[j]) + bf2f(x5[j])) + (bf2f(x6[j]) + bf2f(x7[j]));
        }
    }
    for (; i + 4 <= cnt; i += 4){
        const int s0 = csr_src[beg+i+0]; const int s1 = csr_src[beg+i+1];
        const int s2 = csr_src[beg+i+2]; const int s3 = csr_src[beg+i+3];
        const u16x8 x0 = *(const u16x8*)(g + (size_t)s0*64 + c8);
        const u16x8 x1 = *(const u16x8*)(g + (size_t)s1*64 + c8);
        const u16x8 x2 = *(const u16x8*)(g + (size_t)s2*64 + c8);
        const u16x8 x3 = *(const u16x8*)(g + (size_t)s3*64 + c8);
        #pragma unroll
        for (int j = 0; j < 8; ++j)
            acc[j] += (bf2f(x0[j]) + bf2f(x1[j])) + (bf2f(x2[j]) + bf2f(x3[j]));
    }
    for (; i < cnt; ++i){
        const u16x8 x0 = *(const u16x8*)(g + (size_t)csr_src[beg+i]*64 + c8);
        #pragma unroll
        for (int j = 0; j < 8; ++j) acc[j] += bf2f(x0[j]);
    }

    if (ok){
        const float dv = dinv[v];
        float4 r0, r1;
        const float4 b0 = *(const float4*)(b + c8);
        const float4 b1 = *(const float4*)(b + c8 + 4);
        r0.x = fmaxf(fmaf(acc[0], dv, b0.x), 0.f);
        r0.y = fmaxf(fmaf(acc[1], dv, b0.y), 0.f);
        r0.z = fmaxf(fmaf(acc[2], dv, b0.z), 0.f);
        r0.w = fmaxf(fmaf(acc[3], dv, b0.w), 0.f);
        r1.x = fmaxf(fmaf(acc[4], dv, b1.x), 0.f);
        r1.y = fmaxf(fmaf(acc[5], dv, b1.y), 0.f);
        r1.z = fmaxf(fmaf(acc[6], dv, b1.z), 0.f);
        r1.w = fmaxf(fmaf(acc[7], dv, b1.w), 0.f);
        *(float4*)(outp + (size_t)v*64 + c8)     = r0;
        *(float4*)(outp + (size_t)v*64 + c8 + 4) = r1;
    }
}

// ---------------- dual head ----------------
__global__ __launch_bounds__(256) void hg_head2(const float* __restrict__ HU, const float* __restrict__ HI,
                                                const float* __restrict__ WlU, const float* __restrict__ WlI,
                                                const float* __restrict__ blU, const float* __restrict__ blI,
                                                float* __restrict__ outU, float* __restrict__ outI,
                                                int NU, int NI, int nbU){
    const int type = (blockIdx.x >= nbU);
    const int blk  = type ? blockIdx.x - nbU : blockIdx.x;
    const float* H  = type ? HI : HU;
    const float* Wl = type ? WlI : WlU;
    const float* bl = type ? blI : blU;
    float* outp     = type ? outI : outU;
    const int N     = type ? NI : NU;

    int v = blk*256 + threadIdx.x;
    if (v >= N) return;
    const float* h = H + (size_t)v*64;
    float a0 = bl[0], a1 = bl[1];
    #pragma unroll
    for (int k4 = 0; k4 < 16; ++k4) {
        const float4 x = *(const float4*)(h + k4*4);
        const float4 wA = *(const float4*)(Wl + k4*8 + 0);
        const float4 wB = *(const float4*)(Wl + k4*8 + 4);
        a0 = fmaf(x.x, wA.x, a0); a1 = fmaf(x.x, wA.y, a1);
        a0 = fmaf(x.y, wA.z, a0); a1 = fmaf(x.y, wA.w, a1);
        a0 = fmaf(x.z, wB.x, a0); a1 = fmaf(x.z, wB.y, a1);
        a0 = fmaf(x.w, wB.z, a0); a1 = fmaf(x.w, wB.w, a1);
    }
    float2 r; r.x = a0; r.y = a1;
    *(float2*)(outp + (size_t)v*2) = r;
}

extern "C" void kernel_launch(void* const* d_in, const int* in_sizes, int n_in,
                              void* d_out, int out_size, void* d_ws, size_t ws_size,
                              hipStream_t stream) {
    const float* x_user = (const float*)d_in[0];
    const float* x_item = (const float*)d_in[1];
    const int*  ei_user = (const int*)d_in[2];
    const int*  ei_item = (const int*)d_in[3];
    const float* W1_user = (const float*)d_in[4];
    const float* b1_user = (const float*)d_in[5];
    const float* W1_item = (const float*)d_in[6];
    const float* b1_item = (const float*)d_in[7];
    const float* W2_user = (const float*)d_in[8];
    const float* b2_user = (const float*)d_in[9];
    const float* W2_item = (const float*)d_in[10];
    const float* b2_item = (const float*)d_in[11];
    const float* Wl_user = (const float*)d_in[12];
    const float* bl_user = (const float*)d_in[13];
    const float* Wl_item = (const float*)d_in[14];
    const float* bl_item = (const float*)d_in[15];

    const int NU = in_sizes[0] / 128;
    const int NI = in_sizes[1] / 128;
    const int EU = in_sizes[2] / 2;
    const int EI = in_sizes[3] / 2;
    const int NBU = CDIV(NU, NPB);
    const int NBI = CDIV(NI, NPB);

    char* w = (char*)d_ws;
    float* hFU = (float*)w;                     w += (size_t)NU * 64 * sizeof(float);
    float* hFI = (float*)w;                     w += (size_t)NI * 64 * sizeof(float);
    unsigned short* GU = (unsigned short*)w;    w += (size_t)NU * 64 * sizeof(unsigned short);
    unsigned short* GI = (unsigned short*)w;    w += (size_t)NI * 64 * sizeof(unsigned short);
    float* dinvU = (float*)w;                   w += (size_t)NU * sizeof(float);
    float* dinvI = (float*)w;                   w += (size_t)NI * sizeof(float);
    int* rowptrU = (int*)w;                     w += ((size_t)NU + 1) * sizeof(int);
    int* rowptrI = (int*)w;                     w += ((size_t)NI + 1) * sizeof(int);
    int* csrU = (int*)w;                        w += (size_t)EU * sizeof(int);
    int* csrI = (int*)w;                        w += (size_t)EI * sizeof(int);
    unsigned int* bkU = (unsigned int*)w;       w += (size_t)EU * sizeof(int);
    unsigned int* bkI = (unsigned int*)w;       w += (size_t)EI * sizeof(int);
    int* bhU = (int*)w;                         w += (size_t)NBU * sizeof(int);
    int* bhI = (int*)w;                         w += (size_t)NBI * sizeof(int);   // contiguous with bhU
    int* boffU = (int*)w;                       w += ((size_t)NBU + 1) * sizeof(int);
    int* boffI = (int*)w;                       w += ((size_t)NBI + 1) * sizeof(int);
    int* gcurU = (int*)w;                       w += (size_t)NBU * sizeof(int);
    int* gcurI = (int*)w;                       w += (size_t)NBI * sizeof(int);
    unsigned short* Bhi = (unsigned short*)w;   w += (size_t)24576 * sizeof(unsigned short);
    unsigned short* Blo = (unsigned short*)w;   w += (size_t)24576 * sizeof(unsigned short);

    float* out  = (float*)d_out;
    float* outU = out;
    float* outI = out + (size_t)2 * NU;

    const int NB = (NBU > NBI) ? NBU : NBI;

    // weight prep (independent of everything else)
    hg_wsplit_all<<<12, 256, 0, stream>>>(W1_user, W1_item, W2_user, W2_item, Bhi, Blo);

    // CSR build, both types in each launch
    hipMemsetAsync(bhU, 0, ((size_t)NBU + NBI) * sizeof(int), stream);
    const int hbUc = CDIV(EU, 4096), hbIc = CDIV(EI, 4096);
    hg_bhist2<<<hbUc + hbIc, 256, NB*sizeof(int), stream>>>(ei_user + EU, ei_item + EI, bhU, bhI, EU, EI, hbUc, NB);
    hg_bscan2<<<2, 1024, 0, stream>>>(bhU, bhI, boffU, boffI, gcurU, gcurI, NB, EU, EI);
    const int pbU = CDIV(EU, PCHUNK), pbI = CDIV(EI, PCHUNK);
    const size_t p4lds = (size_t)(3*NB + 256 + 2*PCHUNK) * sizeof(int);
    hg_partition4<<<pbU + pbI, 256, p4lds, stream>>>(ei_user, ei_item, gcurU, gcurI, bkU, bkI, EU, EI, pbU, NB);
    hg_bucket_build2<<<NBU + NBI, 256, 0, stream>>>(bkU, bkI, boffU, boffI, dinvU, dinvI,
                                                    rowptrU, rowptrI, csrU, csrI, NU, NI, EU, EI, NBU);

    // layer 1 (K=128): x -> G -> hF
    const int gbU = CDIV(NU, 64), gbI = CDIV(NI, 64);
    hg_gemm_mfma2<128><<<gbU + gbI, 256, 0, stream>>>(x_user, x_item, Bhi, Blo, 0, 8192,
                                                      dinvU, dinvI, GU, GI, NU, NI, gbU);
    const int abU = CDIV(NU, 32), abI = CDIV(NI, 32);
    hg_aggregate2<<<abU + abI, 256, 0, stream>>>(GU, GI, csrU, csrI, rowptrU, rowptrI,
                                                 dinvU, dinvI, b1_user, b1_item, hFU, hFI, NU, NI, abU);

    // layer 2 (K=64): hF -> G -> hF
    hg_gemm_mfma2<64><<<gbU + gbI, 256, 0, stream>>>(hFU, hFI, Bhi, Blo, 16384, 20480,
                                                     dinvU, dinvI, GU, GI, NU, NI, gbU);
    hg_aggregate2<<<abU + abI, 256, 0, stream>>>(GU, GI, csrU, csrI, rowptrU, rowptrI,
                                                 dinvU, dinvI, b2_user, b2_item, hFU, hFI, NU, NI, abU);

    // head
    const int hdU = CDIV(NU, 256), hdI = CDIV(NI, 256);
    hg_head2<<<hdU + hdI, 256, 0, stream>>>(hFU, hFI, Wl_user, Wl_item, bl_user, bl_item,
                                            outU, outI, NU, NI, hdU);
}